// Round 3
// baseline (1247.941 us; speedup 1.0000x reference)
//
#include <hip/hip_runtime.h>
#include <hip/hip_bf16.h>
#include <stdint.h>

#define NHQ   16
#define NHKV  8
#define DH    128
#define TSEQ  2048
#define HIDN  2048
#define IMID  8192
#define EPS   1e-6f
#define SCL   0.08838834764831845f  // 1/sqrt(128)

typedef __attribute__((ext_vector_type(8))) short short8;
typedef __attribute__((ext_vector_type(4))) short short4v;
typedef __attribute__((ext_vector_type(4))) float f32x4;
typedef unsigned int u32;
typedef unsigned short u16;

__device__ __forceinline__ float b2f(short s) {
  union { u32 u; float f; } cv; cv.u = ((u32)(u16)s) << 16; return cv.f;
}
__device__ __forceinline__ short f2b(float f) {
  union { float f; u32 u; } cv; cv.f = f;
  u32 u = cv.u;
  u32 r = u + 0x7FFFu + ((u >> 16) & 1u);
  return (short)(r >> 16);
}

// async 16B global -> LDS (dest = wave-uniform base + lane*16)  [m97-verified]
__device__ __forceinline__ void gll16(const void* g, void* l) {
  __builtin_amdgcn_global_load_lds(
      (const __attribute__((address_space(1))) u32*)g,
      (__attribute__((address_space(3))) u32*)l, 16, 0, 0);
}

// ---------------------------------------------------------------------------
// C = A @ B^T.  A: bf16 (M,K) lda (our activations).  B: fp32 (N,K) (input
// weights), converted to bf16 during LDS staging.  fp32 accum.
// 128x128 tile, BK=64, 256 thr (2x2 waves, 64x64 each, 4x4 16x16x32 MFMAs).
// EPI: 0 = bf16 store; 1 = fp32 store + bf16 residual; 2 = fp32 store + fp32 residual
// ---------------------------------------------------------------------------
template<int EPI>
__global__ __launch_bounds__(256)
void gemm_bt(const short* __restrict__ A, int lda,
             const float* __restrict__ B,
             const void* __restrict__ RES,
             void* __restrict__ C, int N, int K)
{
  __shared__ __attribute__((aligned(16))) short As[128*64];
  __shared__ __attribute__((aligned(16))) short Bs[128*64];

  const int tid = threadIdx.x;
  const int wv = tid >> 6, ln = tid & 63;
  const int wm = wv >> 1, wn = wv & 1;
  const int l15 = ln & 15, quad = ln >> 4;
  const int bn0 = blockIdx.x * 128, bm0 = blockIdx.y * 128;

  f32x4 acc[4][4];
  #pragma unroll
  for (int i = 0; i < 4; ++i)
    #pragma unroll
    for (int j = 0; j < 4; ++j) acc[i][j] = (f32x4){0.f,0.f,0.f,0.f};

  const int srow = wv*32 + (ln >> 3);  // A row this lane stages (+= i*8)
  const int schk = ln & 7;             // A 16B chunk this lane stages
  const int brow = tid >> 4;           // B row this thread stages (+= p*16)
  const int bcol = (tid & 15) * 4;     // B 4-float group

  for (int kt = 0; kt < K; kt += 64) {
    // A: bf16, async direct-to-LDS
    #pragma unroll
    for (int i = 0; i < 4; ++i) {
      const int r = srow + i*8;
      gll16(A + (size_t)(bm0 + r)*lda + kt + schk*8,
            (char*)As + (wv*32 + i*8)*128);
    }
    // B: fp32 -> bf16 convert-on-stage
    #pragma unroll
    for (int p = 0; p < 8; ++p) {
      const int r = p*16 + brow;
      f32x4 w4 = *(const f32x4*)(B + (size_t)(bn0 + r)*K + kt + bcol);
      short4v s4;
      #pragma unroll
      for (int j = 0; j < 4; ++j) s4[j] = f2b(w4[j]);
      *(short4v*)(Bs + r*64 + bcol) = s4;
    }
    __syncthreads();

    #pragma unroll
    for (int ks = 0; ks < 2; ++ks) {
      short8 af[4], bfr[4];
      #pragma unroll
      for (int mi = 0; mi < 4; ++mi) {
        const int r = wm*64 + mi*16 + l15;
        af[mi] = *(const short8*)(As + r*64 + (quad + ks*4)*8);
      }
      #pragma unroll
      for (int ni = 0; ni < 4; ++ni) {
        const int r = wn*64 + ni*16 + l15;
        bfr[ni] = *(const short8*)(Bs + r*64 + (quad + ks*4)*8);
      }
      #pragma unroll
      for (int mi = 0; mi < 4; ++mi)
        #pragma unroll
        for (int ni = 0; ni < 4; ++ni)
          acc[mi][ni] = __builtin_amdgcn_mfma_f32_16x16x32_bf16(
              af[mi], bfr[ni], acc[mi][ni], 0, 0, 0);
    }
    __syncthreads();
  }

  #pragma unroll
  for (int mi = 0; mi < 4; ++mi) {
    #pragma unroll
    for (int reg = 0; reg < 4; ++reg) {
      const int row = bm0 + wm*64 + mi*16 + quad*4 + reg;
      #pragma unroll
      for (int ni = 0; ni < 4; ++ni) {
        const int col = bn0 + wn*64 + ni*16 + l15;
        const size_t off = (size_t)row*N + col;
        const float v = acc[mi][ni][reg];
        if (EPI == 0)      ((short*)C)[off] = f2b(v);
        else if (EPI == 1) ((float*)C)[off] = b2f(((const short*)RES)[off]) + v;
        else               ((float*)C)[off] = ((const float*)RES)[off] + v;
      }
    }
  }
}

// ---------------------------------------------------------------------------
// fp32 (rows_in, cols_in) -> bf16 (cols_in, rows_in)
// ---------------------------------------------------------------------------
__global__ __launch_bounds__(256)
void transpose_f2b(const float* __restrict__ in, short* __restrict__ out,
                   int rows_in, int cols_in)
{
  __shared__ float tile[64][65];
  const int c0 = blockIdx.x*64, r0 = blockIdx.y*64;
  const int tx = threadIdx.x & 63, ty = threadIdx.x >> 6;
  #pragma unroll
  for (int i = 0; i < 16; ++i) {
    const int r = ty + i*4;
    tile[r][tx] = in[(size_t)(r0+r)*cols_in + c0 + tx];
  }
  __syncthreads();
  #pragma unroll
  for (int i = 0; i < 16; ++i) {
    const int r = ty + i*4;
    out[(size_t)(c0+r)*rows_in + r0 + tx] = f2b(tile[tx][r]);
  }
}

// fp32 (rows_in, cols_in) -> fp32 (cols_in, rows_in)
__global__ __launch_bounds__(256)
void transpose_f2f(const float* __restrict__ in, float* __restrict__ out,
                   int rows_in, int cols_in)
{
  __shared__ float tile[64][65];
  const int c0 = blockIdx.x*64, r0 = blockIdx.y*64;
  const int tx = threadIdx.x & 63, ty = threadIdx.x >> 6;
  #pragma unroll
  for (int i = 0; i < 16; ++i) {
    const int r = ty + i*4;
    tile[r][tx] = in[(size_t)(r0+r)*cols_in + c0 + tx];
  }
  __syncthreads();
  #pragma unroll
  for (int i = 0; i < 16; ++i) {
    const int r = ty + i*4;
    out[(size_t)(c0+r)*rows_in + r0 + tx] = tile[tx][r];
  }
}

// ---------------------------------------------------------------------------
// row RMSNorm over HID=2048. X bf16, W fp32, Y bf16.
// ---------------------------------------------------------------------------
__global__ __launch_bounds__(256)
void rmsnorm_b(const short* __restrict__ X, const float* __restrict__ W,
               short* __restrict__ Y)
{
  const int row = blockIdx.x, tid = threadIdx.x;
  const int wv = tid >> 6, ln = tid & 63;
  const size_t base = (size_t)row*HIDN + tid*8;
  short8 xv = *(const short8*)(X + base);
  float x[8];
  #pragma unroll
  for (int j = 0; j < 8; ++j) x[j] = b2f(xv[j]);
  float s = 0.f;
  #pragma unroll
  for (int j = 0; j < 8; ++j) s += x[j]*x[j];
  #pragma unroll
  for (int off = 32; off; off >>= 1) s += __shfl_xor(s, off, 64);
  __shared__ float red[4];
  if (ln == 0) red[wv] = s;
  __syncthreads();
  const float tot = red[0]+red[1]+red[2]+red[3];
  const float r = rsqrtf(tot*(1.0f/HIDN) + EPS);
  f32x4 w0 = *(const f32x4*)(W + tid*8);
  f32x4 w1 = *(const f32x4*)(W + tid*8 + 4);
  short8 y;
  #pragma unroll
  for (int j = 0; j < 4; ++j) y[j]   = f2b(x[j]*r*w0[j]);
  #pragma unroll
  for (int j = 0; j < 4; ++j) y[j+4] = f2b(x[j+4]*r*w1[j]);
  *(short8*)(Y + base) = y;
}

// X fp32, W fp32, Y bf16
__global__ __launch_bounds__(256)
void rmsnorm_f(const float* __restrict__ X, const float* __restrict__ W,
               short* __restrict__ Y)
{
  const int row = blockIdx.x, tid = threadIdx.x;
  const int wv = tid >> 6, ln = tid & 63;
  const size_t base = (size_t)row*HIDN + tid*8;
  f32x4 a0 = *(const f32x4*)(X + base);
  f32x4 a1 = *(const f32x4*)(X + base + 4);
  float x[8] = {a0[0],a0[1],a0[2],a0[3],a1[0],a1[1],a1[2],a1[3]};
  float s = 0.f;
  #pragma unroll
  for (int j = 0; j < 8; ++j) s += x[j]*x[j];
  #pragma unroll
  for (int off = 32; off; off >>= 1) s += __shfl_xor(s, off, 64);
  __shared__ float red[4];
  if (ln == 0) red[wv] = s;
  __syncthreads();
  const float tot = red[0]+red[1]+red[2]+red[3];
  const float r = rsqrtf(tot*(1.0f/HIDN) + EPS);
  f32x4 w0 = *(const f32x4*)(W + tid*8);
  f32x4 w1 = *(const f32x4*)(W + tid*8 + 4);
  short8 y;
  #pragma unroll
  for (int j = 0; j < 4; ++j) y[j]   = f2b(x[j]*r*w0[j]);
  #pragma unroll
  for (int j = 0; j < 4; ++j) y[j+4] = f2b(x[j+4]*r*w1[j]);
  *(short8*)(Y + base) = y;
}

// ---------------------------------------------------------------------------
// fused per-head RMSNorm (D=128) + RoPE, in-place on bf16 q/k.
// cos/sin/norm-weights fp32.  Lane owns the rot_half pair (d, d+64).
// ---------------------------------------------------------------------------
__global__ __launch_bounds__(64)
void qk_rms_rope(short* __restrict__ Qb, short* __restrict__ Kb,
                 const float* __restrict__ cosb, const float* __restrict__ sinb,
                 const float* __restrict__ qw, const float* __restrict__ kw)
{
  const int b = blockIdx.x;
  const int hi = b % (NHQ + NHKV);
  const int t  = b / (NHQ + NHKV);
  const int ln = threadIdx.x;
  short* row; const float* w;
  if (hi < NHQ) { row = Qb + (size_t)t*(NHQ*DH) + hi*DH; w = qw; }
  else          { row = Kb + (size_t)t*(NHKV*DH) + (hi-NHQ)*DH; w = kw; }
  float x0 = b2f(row[ln]), x1 = b2f(row[ln+64]);
  float s = x0*x0 + x1*x1;
  #pragma unroll
  for (int off = 32; off; off >>= 1) s += __shfl_xor(s, off, 64);
  const float r = rsqrtf(s*(1.0f/DH) + EPS);
  const float n0 = x0*r*w[ln];
  const float n1 = x1*r*w[ln+64];
  const float* cr = cosb + (size_t)t*DH;
  const float* sr = sinb + (size_t)t*DH;
  const float c0 = cr[ln], c1 = cr[ln+64];
  const float s0 = sr[ln], s1 = sr[ln+64];
  row[ln]    = f2b(n0*c0 - n1*s0);
  row[ln+64] = f2b(n1*c1 + n0*s1);
}

// ---------------------------------------------------------------------------
// causal flash attention, 16x16x32 MFMA, plain LDS layouts, all bf16.
// grid (T/64, H); block 256 = 4 waves; wave owns 16 q-rows; s-tiles of 64.
// ---------------------------------------------------------------------------
__global__ __launch_bounds__(256)
void flash_attn(const short* __restrict__ Q, const short* __restrict__ Kb,
                const short* __restrict__ Vb, short* __restrict__ O)
{
  __shared__ __attribute__((aligned(16))) short Ks[64*128];  // [s][d]
  __shared__ __attribute__((aligned(16))) short Vt[128*64];  // [d][s]
  __shared__ __attribute__((aligned(16))) short Ps[4*16*64]; // per-wave [m][s]

  const int tid = threadIdx.x, wv = tid >> 6, ln = tid & 63;
  const int l15 = ln & 15, quad = ln >> 4;
  const int hh = blockIdx.y, kvh = hh >> 1;
  const int m0 = blockIdx.x * 64;
  const int qm0 = m0 + wv*16;

  short8 qf[4];
  {
    const short* qb = Q + (size_t)(qm0 + l15)*(NHQ*DH) + hh*DH + quad*8;
    #pragma unroll
    for (int ks = 0; ks < 4; ++ks) qf[ks] = *(const short8*)(qb + ks*32);
  }

  f32x4 oa[8];
  #pragma unroll
  for (int i = 0; i < 8; ++i) oa[i] = (f32x4){0.f,0.f,0.f,0.f};
  float m_r[4] = {-1e30f,-1e30f,-1e30f,-1e30f};
  float l_r[4] = {0.f,0.f,0.f,0.f};

  const int ntile = blockIdx.x + 1;
  for (int st = 0; st < ntile; ++st) {
    const int s0 = st*64;
    __syncthreads();  // previous tile's LDS reads done before overwrite

    #pragma unroll
    for (int it = 0; it < 4; ++it) {
      const int r = (wv*4 + it)*4 + quad;
      gll16(Kb + (size_t)(s0 + r)*(NHKV*DH) + kvh*DH + l15*8,
            (char*)Ks + (wv*4 + it)*1024);
    }
    {
      const int d = tid & 127, sh = tid >> 7;
      #pragma unroll
      for (int cb = 0; cb < 4; ++cb) {
        short8 t8;
        #pragma unroll
        for (int j = 0; j < 8; ++j)
          t8[j] = Vb[(size_t)(s0 + sh*32 + cb*8 + j)*(NHKV*DH) + kvh*DH + d];
        *(short8*)(Vt + d*64 + (sh*4 + cb)*8) = t8;
      }
    }
    __syncthreads();

    // S = Q K^T
    f32x4 sc[4];
    #pragma unroll
    for (int ci = 0; ci < 4; ++ci) {
      f32x4 a = (f32x4){0.f,0.f,0.f,0.f};
      #pragma unroll
      for (int ks = 0; ks < 4; ++ks) {
        const int r = ci*16 + l15;
        short8 kf = *(const short8*)(Ks + r*128 + (quad + ks*4)*8);
        a = __builtin_amdgcn_mfma_f32_16x16x32_bf16(qf[ks], kf, a, 0, 0, 0);
      }
      sc[ci] = a;
    }

    // online softmax (per lane: rows quad*4+reg)
    float alpha[4];
    #pragma unroll
    for (int reg = 0; reg < 4; ++reg) {
      const int grow = qm0 + quad*4 + reg;
      float rmax = -1e30f;
      #pragma unroll
      for (int ci = 0; ci < 4; ++ci) {
        float v = sc[ci][reg]*SCL;
        const int gs = s0 + ci*16 + l15;
        v = (gs <= grow) ? v : -1e30f;
        sc[ci][reg] = v;
        rmax = fmaxf(rmax, v);
      }
      #pragma unroll
      for (int off = 1; off < 16; off <<= 1)
        rmax = fmaxf(rmax, __shfl_xor(rmax, off, 64));
      const float mn = fmaxf(m_r[reg], rmax);
      alpha[reg] = __expf(m_r[reg] - mn);
      m_r[reg] = mn;
      float rsum = 0.f;
      #pragma unroll
      for (int ci = 0; ci < 4; ++ci) {
        const float p = __expf(sc[ci][reg] - mn);
        sc[ci][reg] = p;
        rsum += p;
      }
      #pragma unroll
      for (int off = 1; off < 16; off <<= 1)
        rsum += __shfl_xor(rsum, off, 64);
      l_r[reg] = l_r[reg]*alpha[reg] + rsum;
    }
    #pragma unroll
    for (int ni = 0; ni < 8; ++ni)
      #pragma unroll
      for (int reg = 0; reg < 4; ++reg) oa[ni][reg] *= alpha[reg];

    // P: C-layout regs -> LDS bf16 (per-wave region), plain [m][s]
    #pragma unroll
    for (int ci = 0; ci < 4; ++ci)
      #pragma unroll
      for (int reg = 0; reg < 4; ++reg)
        Ps[wv*1024 + (quad*4 + reg)*64 + ci*16 + l15] = f2b(sc[ci][reg]);

    __syncthreads();

    // O += P V
    #pragma unroll
    for (int ks = 0; ks < 2; ++ks) {
      const int gp = quad + ks*4;
      short8 pf = *(const short8*)(Ps + wv*1024 + l15*64 + gp*8);
      #pragma unroll
      for (int ni = 0; ni < 8; ++ni) {
        const int d = ni*16 + l15;
        short8 vf = *(const short8*)(Vt + d*64 + gp*8);
        oa[ni] = __builtin_amdgcn_mfma_f32_16x16x32_bf16(pf, vf, oa[ni], 0, 0, 0);
      }
    }
  }

  #pragma unroll
  for (int reg = 0; reg < 4; ++reg) {
    const float inv = 1.0f / l_r[reg];
    const int row = qm0 + quad*4 + reg;
    #pragma unroll
    for (int ni = 0; ni < 8; ++ni)
      O[(size_t)row*(NHQ*DH) + hh*DH + ni*16 + l15] = f2b(oa[ni][reg]*inv);
  }
}

// ---------------------------------------------------------------------------
// gate half of gu (T, 2I)  <-  silu(gate) * up, in place (bf16)
// ---------------------------------------------------------------------------
__global__ __launch_bounds__(256)
void silu_mul(short* __restrict__ gu)
{
  const size_t idx = ((size_t)blockIdx.x*256 + threadIdx.x)*8;
  const size_t t = idx / IMID;
  const size_t i = idx % IMID;
  short* gp = gu + t*(2*IMID) + i;
  short8 g8 = *(const short8*)gp;
  short8 u8 = *(const short8*)(gp + IMID);
  short8 o;
  #pragma unroll
  for (int j = 0; j < 8; ++j) {
    const float g = b2f(g8[j]);
    const float u = b2f(u8[j]);
    const float sl = g / (1.f + __expf(-g));
    o[j] = f2b(sl*u);
  }
  *(short8*)gp = o;
}

// ---------------------------------------------------------------------------
extern "C" void kernel_launch(void* const* d_in, const int* in_sizes, int n_in,
                              void* d_out, int out_size, void* d_ws, size_t ws_size,
                              hipStream_t stream)
{
  const float* hc   = (const float*)d_in[0];
  const float* cosb = (const float*)d_in[1];
  const float* sinb = (const float*)d_in[2];
  // d_in[3] causal_mask: analytic; d_in[4] kv_cache: zeros + fully masked
  const float* wq   = (const float*)d_in[5];
  const float* wk   = (const float*)d_in[6];
  const float* wvp  = (const float*)d_in[7];
  const float* wo   = (const float*)d_in[8];
  const float* wgu  = (const float*)d_in[9];
  const float* wdn  = (const float*)d_in[10];
  const float* iln  = (const float*)d_in[11];
  const float* pln  = (const float*)d_in[12];
  const float* qnw  = (const float*)d_in[13];
  const float* knw  = (const float*)d_in[14];

  // workspace map (88 MB peak; gu reuses the dead phase-1 region):
  //   phase 1: xT 0-8 | h 8-16 | q 16-24 | k 24-28 | v 28-32 | ao 32-40
  //   phase 2: gu 0-64 | hid 64-80 (fp32) | h2 80-88
  char* ws = (char*)d_ws;
  short* xT  = (short*)(ws);
  short* h   = (short*)(ws + ((size_t)8  << 20));
  short* q   = (short*)(ws + ((size_t)16 << 20));
  short* k   = (short*)(ws + ((size_t)24 << 20));
  short* v   = (short*)(ws + ((size_t)28 << 20));
  short* ao  = (short*)(ws + ((size_t)32 << 20));
  short* gu  = (short*)(ws);                        // reuse 0-64MB
  float* hid = (float*)(ws + ((size_t)64 << 20));
  short* h2  = (short*)(ws + ((size_t)80 << 20));

  const dim3 b256(256);

  // x^T: fp32 (HID,T) -> bf16 (T,HID)
  transpose_f2b<<<dim3(32,32), b256, 0, stream>>>(hc, xT, HIDN, TSEQ);
  rmsnorm_b<<<dim3(TSEQ), b256, 0, stream>>>(xT, iln, h);

  gemm_bt<0><<<dim3(16,16), b256, 0, stream>>>(h, HIDN, wq, nullptr, q, 2048, 2048);
  gemm_bt<0><<<dim3(8,16),  b256, 0, stream>>>(h, HIDN, wk, nullptr, k, 1024, 2048);
  gemm_bt<0><<<dim3(8,16),  b256, 0, stream>>>(h, HIDN, wvp, nullptr, v, 1024, 2048);

  qk_rms_rope<<<dim3(TSEQ*(NHQ+NHKV)), dim3(64), 0, stream>>>(q, k, cosb, sinb, qnw, knw);

  flash_attn<<<dim3(TSEQ/64, NHQ), b256, 0, stream>>>(q, k, v, ao);

  gemm_bt<1><<<dim3(16,16), b256, 0, stream>>>(ao, 2048, wo, xT, hid, 2048, 2048);
  rmsnorm_f<<<dim3(TSEQ), b256, 0, stream>>>(hid, pln, h2);

  gemm_bt<0><<<dim3(128,16), b256, 0, stream>>>(h2, HIDN, wgu, nullptr, gu, 16384, 2048);
  silu_mul<<<dim3((TSEQ*IMID/8)/256), b256, 0, stream>>>(gu);
  gemm_bt<2><<<dim3(16,16), b256, 0, stream>>>(gu, 2*IMID, wdn, hid, hid, 2048, 8192);

  // hid (T,HID) fp32 -> d_out (HID,T) fp32
  transpose_f2f<<<dim3(32,32), b256, 0, stream>>>(hid, (float*)d_out, TSEQ, HIDN);
}

// Round 4
// 1058.902 us; speedup vs baseline: 1.1785x; 1.1785x over previous
//
#include <hip/hip_runtime.h>
#include <hip/hip_bf16.h>
#include <stdint.h>

#define NHQ   16
#define NHKV  8
#define DH    128
#define TSEQ  2048
#define HIDN  2048
#define IMID  8192
#define EPS   1e-6f
#define SCL   0.08838834764831845f  // 1/sqrt(128)

typedef __attribute__((ext_vector_type(8))) short short8;
typedef __attribute__((ext_vector_type(4))) short short4v;
typedef __attribute__((ext_vector_type(4))) float f32x4;
typedef unsigned int u32;
typedef unsigned short u16;

__device__ __forceinline__ float b2f(short s) {
  union { u32 u; float f; } cv; cv.u = ((u32)(u16)s) << 16; return cv.f;
}
__device__ __forceinline__ short f2b(float f) {
  union { float f; u32 u; } cv; cv.f = f;
  u32 u = cv.u;
  u32 r = u + 0x7FFFu + ((u >> 16) & 1u);
  return (short)(r >> 16);
}

// async 16B global -> LDS (dest = wave-uniform base + lane*16)  [m97-verified]
__device__ __forceinline__ void gll16(const void* g, void* l) {
  __builtin_amdgcn_global_load_lds(
      (const __attribute__((address_space(1))) u32*)g,
      (__attribute__((address_space(3))) u32*)l, 16, 0, 0);
}

// ---------------------------------------------------------------------------
// fp32 -> bf16 weight convert, 8 elems/thread
// ---------------------------------------------------------------------------
__global__ __launch_bounds__(256)
void cvt_f2b(const float* __restrict__ in, short* __restrict__ out)
{
  const size_t i = ((size_t)blockIdx.x*256 + threadIdx.x)*8;
  f32x4 a0 = *(const f32x4*)(in + i);
  f32x4 a1 = *(const f32x4*)(in + i + 4);
  short8 y;
  #pragma unroll
  for (int j = 0; j < 4; ++j) { y[j] = f2b(a0[j]); y[j+4] = f2b(a1[j]); }
  *(short8*)(out + i) = y;
}

// ---------------------------------------------------------------------------
// C = A @ B^T.  A: bf16 (M,K) lda.  B: bf16 (N,K) if !BF32 else fp32 (N,K),
// converted during staging.  fp32 accum.  128x128 tile, BK=64, 256 thr.
// Grid: x = M-tile (fast axis -> consecutive blocks share B tile in L2),
//       y = N-tile.
// LDS XOR chunk swizzle: physical 16B chunk p of row r holds logical chunk
// p ^ (r&7)  ->  ds_read_b128 bank = 4*((q)^(l15&7)): conflict-free phases.
// EPI: 0 = bf16 store; 1 = fp32 store + bf16 residual; 2 = fp32 store + fp32 residual
// ---------------------------------------------------------------------------
template<int EPI, bool BF32>
__global__ __launch_bounds__(256)
void gemm_bt(const short* __restrict__ A, int lda,
             const void* __restrict__ Bp,
             const void* __restrict__ RES,
             void* __restrict__ C, int N, int K)
{
  __shared__ __attribute__((aligned(16))) short As[128*64];
  __shared__ __attribute__((aligned(16))) short Bs[128*64];

  const int tid = threadIdx.x;
  const int wv = tid >> 6, ln = tid & 63;
  const int wm = wv >> 1, wn = wv & 1;
  const int l15 = ln & 15, quad = ln >> 4;
  const int bm0 = blockIdx.x * 128, bn0 = blockIdx.y * 128;

  f32x4 acc[4][4];
  #pragma unroll
  for (int i = 0; i < 4; ++i)
    #pragma unroll
    for (int j = 0; j < 4; ++j) acc[i][j] = (f32x4){0.f,0.f,0.f,0.f};

  const int srow = wv*32 + (ln >> 3);  // staging row base (+= i*8)
  const int schk = ln & 7;             // physical chunk this lane fills
  // fp32-B staging coords
  const int brow = tid >> 4;           // row (+= p*16)
  const int bgrp = tid & 15;           // 4-float group: chunk=bgrp>>1, half=bgrp&1

  for (int kt = 0; kt < K; kt += 64) {
    #pragma unroll
    for (int i = 0; i < 4; ++i) {
      const int r = srow + i*8;
      const int g = schk ^ (r & 7);    // logical chunk for swizzled slot
      gll16(A + (size_t)(bm0 + r)*lda + kt + g*8,
            (char*)As + (wv*32 + i*8)*128);
      if (!BF32)
        gll16((const short*)Bp + (size_t)(bn0 + r)*K + kt + g*8,
              (char*)Bs + (wv*32 + i*8)*128);
    }
    if (BF32) {
      #pragma unroll
      for (int p = 0; p < 8; ++p) {
        const int r = p*16 + brow;
        f32x4 w4 = *(const f32x4*)((const float*)Bp + (size_t)(bn0 + r)*K + kt + bgrp*4);
        short4v s4;
        #pragma unroll
        for (int j = 0; j < 4; ++j) s4[j] = f2b(w4[j]);
        *(short4v*)(Bs + r*64 + (((bgrp >> 1) ^ (r & 7))*8) + (bgrp & 1)*4) = s4;
      }
    }
    __syncthreads();

    #pragma unroll
    for (int ks = 0; ks < 2; ++ks) {
      short8 af[4], bfr[4];
      #pragma unroll
      for (int mi = 0; mi < 4; ++mi) {
        const int r = wm*64 + mi*16 + l15;
        const int p = (quad + ks*4) ^ (r & 7);
        af[mi] = *(const short8*)(As + r*64 + p*8);
      }
      #pragma unroll
      for (int ni = 0; ni < 4; ++ni) {
        const int r = wn*64 + ni*16 + l15;
        const int p = (quad + ks*4) ^ (r & 7);
        bfr[ni] = *(const short8*)(Bs + r*64 + p*8);
      }
      #pragma unroll
      for (int mi = 0; mi < 4; ++mi)
        #pragma unroll
        for (int ni = 0; ni < 4; ++ni)
          acc[mi][ni] = __builtin_amdgcn_mfma_f32_16x16x32_bf16(
              af[mi], bfr[ni], acc[mi][ni], 0, 0, 0);
    }
    __syncthreads();
  }

  #pragma unroll
  for (int mi = 0; mi < 4; ++mi) {
    #pragma unroll
    for (int reg = 0; reg < 4; ++reg) {
      const int row = bm0 + wm*64 + mi*16 + quad*4 + reg;
      #pragma unroll
      for (int ni = 0; ni < 4; ++ni) {
        const int col = bn0 + wn*64 + ni*16 + l15;
        const size_t off = (size_t)row*N + col;
        const float v = acc[mi][ni][reg];
        if (EPI == 0)      ((short*)C)[off] = f2b(v);
        else if (EPI == 1) ((float*)C)[off] = b2f(((const short*)RES)[off]) + v;
        else               ((float*)C)[off] = ((const float*)RES)[off] + v;
      }
    }
  }
}

// ---------------------------------------------------------------------------
// fp32 (rows_in, cols_in) -> bf16 (cols_in, rows_in)
// ---------------------------------------------------------------------------
__global__ __launch_bounds__(256)
void transpose_f2b(const float* __restrict__ in, short* __restrict__ out,
                   int rows_in, int cols_in)
{
  __shared__ float tile[64][65];
  const int c0 = blockIdx.x*64, r0 = blockIdx.y*64;
  const int tx = threadIdx.x & 63, ty = threadIdx.x >> 6;
  #pragma unroll
  for (int i = 0; i < 16; ++i) {
    const int r = ty + i*4;
    tile[r][tx] = in[(size_t)(r0+r)*cols_in + c0 + tx];
  }
  __syncthreads();
  #pragma unroll
  for (int i = 0; i < 16; ++i) {
    const int r = ty + i*4;
    out[(size_t)(c0+r)*rows_in + r0 + tx] = f2b(tile[tx][r]);
  }
}

// fp32 (rows_in, cols_in) -> fp32 (cols_in, rows_in)
__global__ __launch_bounds__(256)
void transpose_f2f(const float* __restrict__ in, float* __restrict__ out,
                   int rows_in, int cols_in)
{
  __shared__ float tile[64][65];
  const int c0 = blockIdx.x*64, r0 = blockIdx.y*64;
  const int tx = threadIdx.x & 63, ty = threadIdx.x >> 6;
  #pragma unroll
  for (int i = 0; i < 16; ++i) {
    const int r = ty + i*4;
    tile[r][tx] = in[(size_t)(r0+r)*cols_in + c0 + tx];
  }
  __syncthreads();
  #pragma unroll
  for (int i = 0; i < 16; ++i) {
    const int r = ty + i*4;
    out[(size_t)(c0+r)*rows_in + r0 + tx] = tile[tx][r];
  }
}

// ---------------------------------------------------------------------------
// row RMSNorm over HID=2048. X bf16, W fp32, Y bf16.
// ---------------------------------------------------------------------------
__global__ __launch_bounds__(256)
void rmsnorm_b(const short* __restrict__ X, const float* __restrict__ W,
               short* __restrict__ Y)
{
  const int row = blockIdx.x, tid = threadIdx.x;
  const int wv = tid >> 6, ln = tid & 63;
  const size_t base = (size_t)row*HIDN + tid*8;
  short8 xv = *(const short8*)(X + base);
  float x[8];
  #pragma unroll
  for (int j = 0; j < 8; ++j) x[j] = b2f(xv[j]);
  float s = 0.f;
  #pragma unroll
  for (int j = 0; j < 8; ++j) s += x[j]*x[j];
  #pragma unroll
  for (int off = 32; off; off >>= 1) s += __shfl_xor(s, off, 64);
  __shared__ float red[4];
  if (ln == 0) red[wv] = s;
  __syncthreads();
  const float tot = red[0]+red[1]+red[2]+red[3];
  const float r = rsqrtf(tot*(1.0f/HIDN) + EPS);
  f32x4 w0 = *(const f32x4*)(W + tid*8);
  f32x4 w1 = *(const f32x4*)(W + tid*8 + 4);
  short8 y;
  #pragma unroll
  for (int j = 0; j < 4; ++j) y[j]   = f2b(x[j]*r*w0[j]);
  #pragma unroll
  for (int j = 0; j < 4; ++j) y[j+4] = f2b(x[j+4]*r*w1[j]);
  *(short8*)(Y + base) = y;
}

// X fp32, W fp32, Y bf16
__global__ __launch_bounds__(256)
void rmsnorm_f(const float* __restrict__ X, const float* __restrict__ W,
               short* __restrict__ Y)
{
  const int row = blockIdx.x, tid = threadIdx.x;
  const int wv = tid >> 6, ln = tid & 63;
  const size_t base = (size_t)row*HIDN + tid*8;
  f32x4 a0 = *(const f32x4*)(X + base);
  f32x4 a1 = *(const f32x4*)(X + base + 4);
  float x[8] = {a0[0],a0[1],a0[2],a0[3],a1[0],a1[1],a1[2],a1[3]};
  float s = 0.f;
  #pragma unroll
  for (int j = 0; j < 8; ++j) s += x[j]*x[j];
  #pragma unroll
  for (int off = 32; off; off >>= 1) s += __shfl_xor(s, off, 64);
  __shared__ float red[4];
  if (ln == 0) red[wv] = s;
  __syncthreads();
  const float tot = red[0]+red[1]+red[2]+red[3];
  const float r = rsqrtf(tot*(1.0f/HIDN) + EPS);
  f32x4 w0 = *(const f32x4*)(W + tid*8);
  f32x4 w1 = *(const f32x4*)(W + tid*8 + 4);
  short8 y;
  #pragma unroll
  for (int j = 0; j < 4; ++j) y[j]   = f2b(x[j]*r*w0[j]);
  #pragma unroll
  for (int j = 0; j < 4; ++j) y[j+4] = f2b(x[j+4]*r*w1[j]);
  *(short8*)(Y + base) = y;
}

// ---------------------------------------------------------------------------
// fused per-head RMSNorm (D=128) + RoPE, in-place on bf16 q/k.
// ---------------------------------------------------------------------------
__global__ __launch_bounds__(64)
void qk_rms_rope(short* __restrict__ Qb, short* __restrict__ Kb,
                 const float* __restrict__ cosb, const float* __restrict__ sinb,
                 const float* __restrict__ qw, const float* __restrict__ kw)
{
  const int b = blockIdx.x;
  const int hi = b % (NHQ + NHKV);
  const int t  = b / (NHQ + NHKV);
  const int ln = threadIdx.x;
  short* row; const float* w;
  if (hi < NHQ) { row = Qb + (size_t)t*(NHQ*DH) + hi*DH; w = qw; }
  else          { row = Kb + (size_t)t*(NHKV*DH) + (hi-NHQ)*DH; w = kw; }
  float x0 = b2f(row[ln]), x1 = b2f(row[ln+64]);
  float s = x0*x0 + x1*x1;
  #pragma unroll
  for (int off = 32; off; off >>= 1) s += __shfl_xor(s, off, 64);
  const float r = rsqrtf(s*(1.0f/DH) + EPS);
  const float n0 = x0*r*w[ln];
  const float n1 = x1*r*w[ln+64];
  const float* cr = cosb + (size_t)t*DH;
  const float* sr = sinb + (size_t)t*DH;
  const float c0 = cr[ln], c1 = cr[ln+64];
  const float s0 = sr[ln], s1 = sr[ln+64];
  row[ln]    = f2b(n0*c0 - n1*s0);
  row[ln+64] = f2b(n1*c1 + n0*s1);
}

// ---------------------------------------------------------------------------
// causal flash attention, 16x16x32 MFMA, plain LDS layouts (unchanged r3).
// ---------------------------------------------------------------------------
__global__ __launch_bounds__(256)
void flash_attn(const short* __restrict__ Q, const short* __restrict__ Kb,
                const short* __restrict__ Vb, short* __restrict__ O)
{
  __shared__ __attribute__((aligned(16))) short Ks[64*128];  // [s][d]
  __shared__ __attribute__((aligned(16))) short Vt[128*64];  // [d][s]
  __shared__ __attribute__((aligned(16))) short Ps[4*16*64]; // per-wave [m][s]

  const int tid = threadIdx.x, wv = tid >> 6, ln = tid & 63;
  const int l15 = ln & 15, quad = ln >> 4;
  const int hh = blockIdx.y, kvh = hh >> 1;
  const int m0 = blockIdx.x * 64;
  const int qm0 = m0 + wv*16;

  short8 qf[4];
  {
    const short* qb = Q + (size_t)(qm0 + l15)*(NHQ*DH) + hh*DH + quad*8;
    #pragma unroll
    for (int ks = 0; ks < 4; ++ks) qf[ks] = *(const short8*)(qb + ks*32);
  }

  f32x4 oa[8];
  #pragma unroll
  for (int i = 0; i < 8; ++i) oa[i] = (f32x4){0.f,0.f,0.f,0.f};
  float m_r[4] = {-1e30f,-1e30f,-1e30f,-1e30f};
  float l_r[4] = {0.f,0.f,0.f,0.f};

  const int ntile = blockIdx.x + 1;
  for (int st = 0; st < ntile; ++st) {
    const int s0 = st*64;
    __syncthreads();

    #pragma unroll
    for (int it = 0; it < 4; ++it) {
      const int r = (wv*4 + it)*4 + quad;
      gll16(Kb + (size_t)(s0 + r)*(NHKV*DH) + kvh*DH + l15*8,
            (char*)Ks + (wv*4 + it)*1024);
    }
    {
      const int d = tid & 127, sh = tid >> 7;
      #pragma unroll
      for (int cb = 0; cb < 4; ++cb) {
        short8 t8;
        #pragma unroll
        for (int j = 0; j < 8; ++j)
          t8[j] = Vb[(size_t)(s0 + sh*32 + cb*8 + j)*(NHKV*DH) + kvh*DH + d];
        *(short8*)(Vt + d*64 + (sh*4 + cb)*8) = t8;
      }
    }
    __syncthreads();

    f32x4 sc[4];
    #pragma unroll
    for (int ci = 0; ci < 4; ++ci) {
      f32x4 a = (f32x4){0.f,0.f,0.f,0.f};
      #pragma unroll
      for (int ks = 0; ks < 4; ++ks) {
        const int r = ci*16 + l15;
        short8 kf = *(const short8*)(Ks + r*128 + (quad + ks*4)*8);
        a = __builtin_amdgcn_mfma_f32_16x16x32_bf16(qf[ks], kf, a, 0, 0, 0);
      }
      sc[ci] = a;
    }

    float alpha[4];
    #pragma unroll
    for (int reg = 0; reg < 4; ++reg) {
      const int grow = qm0 + quad*4 + reg;
      float rmax = -1e30f;
      #pragma unroll
      for (int ci = 0; ci < 4; ++ci) {
        float v = sc[ci][reg]*SCL;
        const int gs = s0 + ci*16 + l15;
        v = (gs <= grow) ? v : -1e30f;
        sc[ci][reg] = v;
        rmax = fmaxf(rmax, v);
      }
      #pragma unroll
      for (int off = 1; off < 16; off <<= 1)
        rmax = fmaxf(rmax, __shfl_xor(rmax, off, 64));
      const float mn = fmaxf(m_r[reg], rmax);
      alpha[reg] = __expf(m_r[reg] - mn);
      m_r[reg] = mn;
      float rsum = 0.f;
      #pragma unroll
      for (int ci = 0; ci < 4; ++ci) {
        const float p = __expf(sc[ci][reg] - mn);
        sc[ci][reg] = p;
        rsum += p;
      }
      #pragma unroll
      for (int off = 1; off < 16; off <<= 1)
        rsum += __shfl_xor(rsum, off, 64);
      l_r[reg] = l_r[reg]*alpha[reg] + rsum;
    }
    #pragma unroll
    for (int ni = 0; ni < 8; ++ni)
      #pragma unroll
      for (int reg = 0; reg < 4; ++reg) oa[ni][reg] *= alpha[reg];

    #pragma unroll
    for (int ci = 0; ci < 4; ++ci)
      #pragma unroll
      for (int reg = 0; reg < 4; ++reg)
        Ps[wv*1024 + (quad*4 + reg)*64 + ci*16 + l15] = f2b(sc[ci][reg]);

    __syncthreads();

    #pragma unroll
    for (int ks = 0; ks < 2; ++ks) {
      const int gp = quad + ks*4;
      short8 pf = *(const short8*)(Ps + wv*1024 + l15*64 + gp*8);
      #pragma unroll
      for (int ni = 0; ni < 8; ++ni) {
        const int d = ni*16 + l15;
        short8 vf = *(const short8*)(Vt + d*64 + gp*8);
        oa[ni] = __builtin_amdgcn_mfma_f32_16x16x32_bf16(pf, vf, oa[ni], 0, 0, 0);
      }
    }
  }

  #pragma unroll
  for (int reg = 0; reg < 4; ++reg) {
    const float inv = 1.0f / l_r[reg];
    const int row = qm0 + quad*4 + reg;
    #pragma unroll
    for (int ni = 0; ni < 8; ++ni)
      O[(size_t)row*(NHQ*DH) + hh*DH + ni*16 + l15] = f2b(oa[ni][reg]*inv);
  }
}

// ---------------------------------------------------------------------------
// gate half of gu (T, 2I)  <-  silu(gate) * up, in place (bf16)
// ---------------------------------------------------------------------------
__global__ __launch_bounds__(256)
void silu_mul(short* __restrict__ gu)
{
  const size_t idx = ((size_t)blockIdx.x*256 + threadIdx.x)*8;
  const size_t t = idx / IMID;
  const size_t i = idx % IMID;
  short* gp = gu + t*(2*IMID) + i;
  short8 g8 = *(const short8*)gp;
  short8 u8 = *(const short8*)(gp + IMID);
  short8 o;
  #pragma unroll
  for (int j = 0; j < 8; ++j) {
    const float g = b2f(g8[j]);
    const float u = b2f(u8[j]);
    const float sl = g / (1.f + __expf(-g));
    o[j] = f2b(sl*u);
  }
  *(short8*)gp = o;
}

// ---------------------------------------------------------------------------
extern "C" void kernel_launch(void* const* d_in, const int* in_sizes, int n_in,
                              void* d_out, int out_size, void* d_ws, size_t ws_size,
                              hipStream_t stream)
{
  const float* hc   = (const float*)d_in[0];
  const float* cosb = (const float*)d_in[1];
  const float* sinb = (const float*)d_in[2];
  const float* wq   = (const float*)d_in[5];
  const float* wk   = (const float*)d_in[6];
  const float* wvp  = (const float*)d_in[7];
  const float* wo   = (const float*)d_in[8];
  const float* wgu  = (const float*)d_in[9];
  const float* wdn  = (const float*)d_in[10];
  const float* iln  = (const float*)d_in[11];
  const float* pln  = (const float*)d_in[12];
  const float* qnw  = (const float*)d_in[13];
  const float* knw  = (const float*)d_in[14];

  // workspace map (192 MB peak):
  //  wgu_b 0-64 | wq_b 64-72 | wk_b 72-76 | wv_b 76-80 | wo_b 80-88
  //  xT 88-96 | h 96-104 | q 104-112 | k 112-116 | v 116-120 | ao 120-128
  //  hid (fp32) 104-120 (over q/k/v, dead after flash)
  //  h2 120-128 (over ao, dead after wo-gemm) | gu 128-192
  char* ws = (char*)d_ws;
  short* wgu_b = (short*)(ws);
  short* wq_b  = (short*)(ws + ((size_t)64 << 20));
  short* wk_b  = (short*)(ws + ((size_t)72 << 20));
  short* wv_b  = (short*)(ws + ((size_t)76 << 20));
  short* wo_b  = (short*)(ws + ((size_t)80 << 20));
  short* xT    = (short*)(ws + ((size_t)88 << 20));
  short* h     = (short*)(ws + ((size_t)96 << 20));
  short* q     = (short*)(ws + ((size_t)104 << 20));
  short* k     = (short*)(ws + ((size_t)112 << 20));
  short* v     = (short*)(ws + ((size_t)116 << 20));
  short* ao    = (short*)(ws + ((size_t)120 << 20));
  float* hid   = (float*)(ws + ((size_t)104 << 20));
  short* h2    = (short*)(ws + ((size_t)120 << 20));
  short* gu    = (short*)(ws + ((size_t)128 << 20));

  const dim3 b256(256);

  // weight pre-convert (fp32 -> bf16)
  cvt_f2b<<<dim3(16384), b256, 0, stream>>>(wgu, wgu_b);  // 32M elems
  cvt_f2b<<<dim3(2048),  b256, 0, stream>>>(wq,  wq_b);   // 4M
  cvt_f2b<<<dim3(1024),  b256, 0, stream>>>(wk,  wk_b);   // 2M
  cvt_f2b<<<dim3(1024),  b256, 0, stream>>>(wvp, wv_b);   // 2M
  cvt_f2b<<<dim3(2048),  b256, 0, stream>>>(wo,  wo_b);   // 4M

  transpose_f2b<<<dim3(32,32), b256, 0, stream>>>(hc, xT, HIDN, TSEQ);
  rmsnorm_b<<<dim3(TSEQ), b256, 0, stream>>>(xT, iln, h);

  gemm_bt<0,false><<<dim3(16,16), b256, 0, stream>>>(h, HIDN, wq_b, nullptr, q, 2048, 2048);
  gemm_bt<0,false><<<dim3(16,8),  b256, 0, stream>>>(h, HIDN, wk_b, nullptr, k, 1024, 2048);
  gemm_bt<0,false><<<dim3(16,8),  b256, 0, stream>>>(h, HIDN, wv_b, nullptr, v, 1024, 2048);

  qk_rms_rope<<<dim3(TSEQ*(NHQ+NHKV)), dim3(64), 0, stream>>>(q, k, cosb, sinb, qnw, knw);

  flash_attn<<<dim3(TSEQ/64, NHQ), b256, 0, stream>>>(q, k, v, ao);

  gemm_bt<1,false><<<dim3(16,16), b256, 0, stream>>>(ao, 2048, wo_b, xT, hid, 2048, 2048);
  rmsnorm_f<<<dim3(TSEQ), b256, 0, stream>>>(hid, pln, h2);

  gemm_bt<0,false><<<dim3(16,128), b256, 0, stream>>>(h2, HIDN, wgu_b, nullptr, gu, 16384, 2048);
  silu_mul<<<dim3((TSEQ*IMID/8)/256), b256, 0, stream>>>(gu);
  gemm_bt<2,true><<<dim3(16,16), b256, 0, stream>>>(gu, 2*IMID, wdn, hid, hid, 2048, 8192);

  transpose_f2f<<<dim3(32,32), b256, 0, stream>>>(hid, (float*)d_out, TSEQ, HIDN);
}